// Round 3
// baseline (192.741 us; speedup 1.0000x reference)
//
#include <hip/hip_runtime.h>
#include <math.h>

// VAE loss: anneal * mean_n(KLD_n) + mean_n(NLL_n)
//   KLD_n = sum_d 0.5*(-lv + exp(lv) + mu^2 - 1)
//   NLL_n = logsumexp(row_n) - row_n[y_n]
// N=8192 rows, V=32000 fp32 cols (1.05 GB -> memory bound).
//
// R2 theory: 320-thr blocks (5 waves) gave 6 blocks/CU = 1536 slots ->
// 8192/1536 = 5.33 rounds -> 2/3 of slots idle the last ~32us (~11% loss).
// Fix: 256-thr blocks + __launch_bounds__(256,8) -> 8 blocks/CU = 2048
// slots -> exactly 4 rounds, no quantization idle.

#define N_ROWS 8192
#define V_COLS 32000
#define LATENT_D 64
#define THREADS 256          // 4 waves; 8 blocks/CU
#define FULL_ITERS 31        // 8000 float4 = 31*256 + 64 (tail by t<64)

__device__ __forceinline__ void combine_ms(float& m, float& s, float m2, float s2) {
    float M = fmaxf(m, m2);
    s = s * __expf(m - M) + s2 * __expf(m2 - M);   // exp(-inf)=0 handles init
    m = M;
}

__global__ __launch_bounds__(THREADS, 8) void vae_row_kernel(
    const float* __restrict__ dec,      // [N, V]
    const float* __restrict__ mu,       // [N, 64]
    const float* __restrict__ logvar,   // [N, 64]
    const int*   __restrict__ y,        // [N]
    const float* __restrict__ anneal,   // [1]
    float*       __restrict__ partial)  // [N] (d_ws)
{
    const int n = blockIdx.x;
    const int t = threadIdx.x;
    const float* row = dec + (size_t)n * V_COLS;
    const float4* row4 = (const float4*)row;

    // Early-issue the true-class gather + anneal load; latency hides under
    // the streaming loop (only t==0 consumes them, at the very end).
    float xy = 0.0f, ann = 0.0f;
    if (t == 0) { xy = row[y[n]]; ann = anneal[0]; }

    // ---- one-pass branchless online softmax over this thread's chunk ----
    float m = -INFINITY, s = 0.0f;
    #pragma unroll 4
    for (int j = 0; j < FULL_ITERS; ++j) {
        float4 v = row4[t + j * THREADS];
        float lm = fmaxf(fmaxf(v.x, v.y), fmaxf(v.z, v.w));
        float M  = fmaxf(m, lm);
        s = s * __expf(m - M)
          + __expf(v.x - M) + __expf(v.y - M)
          + __expf(v.z - M) + __expf(v.w - M);
        m = M;
    }
    if (t < 64) {  // tail: float4 indices 7936..7999
        float4 v = row4[FULL_ITERS * THREADS + t];
        float lm = fmaxf(fmaxf(v.x, v.y), fmaxf(v.z, v.w));
        float M  = fmaxf(m, lm);
        s = s * __expf(m - M)
          + __expf(v.x - M) + __expf(v.y - M)
          + __expf(v.z - M) + __expf(v.w - M);
        m = M;
    }

    // ---- wave (64-lane) butterfly reduce of (m, s) ----
    #pragma unroll
    for (int off = 1; off < 64; off <<= 1) {
        float m2 = __shfl_xor(m, off, 64);
        float s2 = __shfl_xor(s, off, 64);
        combine_ms(m, s, m2, s2);
    }

    // ---- fused per-row KLD over the 64 latent dims (wave 0) ----
    float k = 0.0f;
    if (t < 64) {
        float lv = logvar[n * LATENT_D + t];
        float mq = mu[n * LATENT_D + t];
        k = 0.5f * (-lv + __expf(lv) + mq * mq - 1.0f);
        #pragma unroll
        for (int off = 1; off < 64; off <<= 1)
            k += __shfl_xor(k, off, 64);
    }

    // ---- cross-wave (4 waves) combine via LDS, single sync ----
    __shared__ float sm[4], ss[4];
    const int wave = t >> 6, lane = t & 63;
    if (lane == 0) { sm[wave] = m; ss[wave] = s; }
    __syncthreads();
    if (t == 0) {
        float M = sm[0], S = ss[0];
        #pragma unroll
        for (int w = 1; w < 4; ++w) combine_ms(M, S, sm[w], ss[w]);
        float nll = (M + __logf(S)) - xy;      // -log_softmax(row)[y]
        partial[n] = ann * k + nll;
    }
}

__global__ __launch_bounds__(256) void vae_reduce_kernel(
    const float* __restrict__ partial, float* __restrict__ out)
{
    const int t = threadIdx.x;
    float s = 0.0f;
    for (int i = t; i < N_ROWS; i += 256) s += partial[i];
    #pragma unroll
    for (int off = 1; off < 64; off <<= 1) s += __shfl_xor(s, off, 64);
    __shared__ float ws[4];
    const int wave = t >> 6, lane = t & 63;
    if (lane == 0) ws[wave] = s;
    __syncthreads();
    if (t == 0)
        out[0] = (ws[0] + ws[1] + ws[2] + ws[3]) / (float)N_ROWS;
}

extern "C" void kernel_launch(void* const* d_in, const int* in_sizes, int n_in,
                              void* d_out, int out_size, void* d_ws, size_t ws_size,
                              hipStream_t stream) {
    const float* dec    = (const float*)d_in[0];
    const float* mu     = (const float*)d_in[1];
    const float* logvar = (const float*)d_in[2];
    const int*   y      = (const int*)d_in[3];
    const float* anneal = (const float*)d_in[4];
    float* out = (float*)d_out;
    float* partial = (float*)d_ws;   // 8192 floats = 32 KB

    vae_row_kernel<<<N_ROWS, THREADS, 0, stream>>>(dec, mu, logvar, y, anneal, partial);
    vae_reduce_kernel<<<1, 256, 0, stream>>>(partial, out);
}

// Round 5
// 165.631 us; speedup vs baseline: 1.1637x; 1.1637x over previous
//
#include <hip/hip_runtime.h>
#include <math.h>

// VAE loss: anneal * mean_n(KLD_n) + mean_n(NLL_n)
//   KLD_n = sum_d 0.5*(-lv + exp(lv) + mu^2 - 1)
//   NLL_n = logsumexp(row_n) - row_n[y_n]
// N=8192 rows, V=32000 fp32 cols (1.05 GB -> memory bound).
//
// R3 result: three structurally different schedules all ~191us (+-1%) ->
// memory-system-limited (~5.5 TB/s), not scheduling.
// R5: retry R4's non-temporal-load probe; __builtin_nontemporal_load needs a
// clang native vector type, not HIP's float4 struct.

#define N_ROWS 8192
#define V_COLS 32000
#define LATENT_D 64
#define THREADS 320        // 5 waves
#define ITERS 25           // (V_COLS/4) / THREADS, exact

typedef float vfloat4 __attribute__((ext_vector_type(4)));

__device__ __forceinline__ void combine_ms(float& m, float& s, float m2, float s2) {
    float M = fmaxf(m, m2);
    s = s * __expf(m - M) + s2 * __expf(m2 - M);   // exp(-inf)=0 handles init
    m = M;
}

__global__ __launch_bounds__(THREADS) void vae_row_kernel(
    const float* __restrict__ dec,      // [N, V]
    const float* __restrict__ mu,       // [N, 64]
    const float* __restrict__ logvar,   // [N, 64]
    const int*   __restrict__ y,        // [N]
    const float* __restrict__ anneal,   // [1]
    float*       __restrict__ partial)  // [N] (d_ws)
{
    const int n = blockIdx.x;
    const int t = threadIdx.x;
    const float* row = dec + (size_t)n * V_COLS;
    const vfloat4* row4 = (const vfloat4*)row;

    // Early-issue the true-class gather + anneal load; latency hides under
    // the streaming loop (only t==0 consumes them, at the very end).
    float xy = 0.0f, ann = 0.0f;
    if (t == 0) { xy = row[y[n]]; ann = anneal[0]; }

    // ---- one-pass branchless online softmax, non-temporal stream ----
    float m = -INFINITY, s = 0.0f;
    #pragma unroll 5
    for (int j = 0; j < ITERS; ++j) {
        vfloat4 v = __builtin_nontemporal_load(&row4[t + j * THREADS]);
        float lm = fmaxf(fmaxf(v.x, v.y), fmaxf(v.z, v.w));
        float M  = fmaxf(m, lm);
        s = s * __expf(m - M)
          + __expf(v.x - M) + __expf(v.y - M)
          + __expf(v.z - M) + __expf(v.w - M);
        m = M;
    }

    // ---- wave (64-lane) butterfly reduce of (m, s) ----
    #pragma unroll
    for (int off = 1; off < 64; off <<= 1) {
        float m2 = __shfl_xor(m, off, 64);
        float s2 = __shfl_xor(s, off, 64);
        combine_ms(m, s, m2, s2);
    }

    // ---- fused per-row KLD over the 64 latent dims (wave 0) ----
    float k = 0.0f;
    if (t < 64) {
        float lv = logvar[n * LATENT_D + t];
        float mq = mu[n * LATENT_D + t];
        k = 0.5f * (-lv + __expf(lv) + mq * mq - 1.0f);
        #pragma unroll
        for (int off = 1; off < 64; off <<= 1)
            k += __shfl_xor(k, off, 64);
    }

    // ---- cross-wave (5 waves) combine via LDS, single sync ----
    __shared__ float sm[5], ss[5];
    const int wave = t >> 6, lane = t & 63;
    if (lane == 0) { sm[wave] = m; ss[wave] = s; }
    __syncthreads();
    if (t == 0) {
        float M = sm[0], S = ss[0];
        #pragma unroll
        for (int w = 1; w < 5; ++w) combine_ms(M, S, sm[w], ss[w]);
        float nll = (M + __logf(S)) - xy;      // -log_softmax(row)[y]
        partial[n] = ann * k + nll;
    }
}

__global__ __launch_bounds__(256) void vae_reduce_kernel(
    const float* __restrict__ partial, float* __restrict__ out)
{
    const int t = threadIdx.x;
    float s = 0.0f;
    for (int i = t; i < N_ROWS; i += 256) s += partial[i];
    #pragma unroll
    for (int off = 1; off < 64; off <<= 1) s += __shfl_xor(s, off, 64);
    __shared__ float ws[4];
    const int wave = t >> 6, lane = t & 63;
    if (lane == 0) ws[wave] = s;
    __syncthreads();
    if (t == 0)
        out[0] = (ws[0] + ws[1] + ws[2] + ws[3]) / (float)N_ROWS;
}

extern "C" void kernel_launch(void* const* d_in, const int* in_sizes, int n_in,
                              void* d_out, int out_size, void* d_ws, size_t ws_size,
                              hipStream_t stream) {
    const float* dec    = (const float*)d_in[0];
    const float* mu     = (const float*)d_in[1];
    const float* logvar = (const float*)d_in[2];
    const int*   y      = (const int*)d_in[3];
    const float* anneal = (const float*)d_in[4];
    float* out = (float*)d_out;
    float* partial = (float*)d_ws;   // 8192 floats = 32 KB

    vae_row_kernel<<<N_ROWS, THREADS, 0, stream>>>(dec, mu, logvar, y, anneal, partial);
    vae_reduce_kernel<<<1, 256, 0, stream>>>(partial, out);
}